// Round 4
// baseline (729.801 us; speedup 1.0000x reference)
//
#include <hip/hip_runtime.h>
#include <math.h>

#define NPIX 262144   // 512*512
#define FSTR 513      // LDS column stride for batch-8 FFT (pad 512+1)

__device__ __forceinline__ int brev9(int i) { return (int)(__brev((unsigned)i) >> 23); }

__device__ __forceinline__ void init_tw(float* twr, float* twi, int t) {
  if (t < 256) {
    float ang = -3.14159265358979323846f * (float)t / 256.0f;
    float s, c;
    sincosf(ang, &s, &c);
    twr[t] = c; twi[t] = s;
  }
}

// 8 x 512-pt radix-2 DIT FFTs in LDS, column-major: element p of FFT c at
// [c*FSTR + p]. 256 threads: c = t>>5, 32 threads x 8 butterflies/stage/FFT.
template<bool FWD>
__device__ __forceinline__ void fft512x8(float* __restrict__ sr, float* __restrict__ si,
                                         const float* __restrict__ twr,
                                         const float* __restrict__ twi, int t) {
  const int c  = t >> 5;
  const int k0 = t & 31;
  float* cr = sr + c * FSTR;
  float* ci = si + c * FSTR;
  #pragma unroll
  for (int s = 0; s < 9; s++) {
    const int half = 1 << s;
    __syncthreads();
    #pragma unroll
    for (int m = 0; m < 8; m++) {
      int k  = k0 + 32 * m;
      int j  = k & (half - 1);
      int k2 = ((k >> s) << (s + 1)) | j;
      int tk = j << (8 - s);
      float wr = twr[tk];
      float wi = FWD ? twi[tk] : -twi[tk];
      float vr = cr[k2 + half], vi = ci[k2 + half];
      float tr = vr * wr - vi * wi;
      float ti = vr * wi + vi * wr;
      float ur = cr[k2], ui = ci[k2];
      cr[k2] = ur + tr;        ci[k2] = ui + ti;
      cr[k2 + half] = ur - tr; ci[k2 + half] = ui - ti;
    }
  }
  __syncthreads();
}

// forward FFT over 8 contiguous rows per block (real input).
__global__ __launch_bounds__(256) void k_fft_rows(const float* __restrict__ x,
                                                  float2* __restrict__ xf) {
  __shared__ float sr[8 * FSTR], si[8 * FSTR], twr[256], twi[256];
  int t = threadIdx.x;
  int img = blockIdx.x >> 6;
  int r0 = (blockIdx.x & 63) << 3;
  init_tw(twr, twi, t);
  const float4* p4 = (const float4*)(x + (size_t)img * NPIX + (size_t)r0 * 512);
  for (int e = t; e < 1024; e += 256) {
    int row = e >> 7, w = e & 127;
    float4 f = p4[e];
    float* cr = sr + row * FSTR;
    float* ci = si + row * FSTR;
    int p = 4 * w;
    cr[brev9(p)]     = f.x;  ci[brev9(p)]     = 0.0f;
    cr[brev9(p + 1)] = f.y;  ci[brev9(p + 1)] = 0.0f;
    cr[brev9(p + 2)] = f.z;  ci[brev9(p + 2)] = 0.0f;
    cr[brev9(p + 3)] = f.w;  ci[brev9(p + 3)] = 0.0f;
  }
  fft512x8<true>(sr, si, twr, twi, t);
  float4* q4 = (float4*)(xf + (size_t)img * NPIX + (size_t)r0 * 512);
  for (int e = t; e < 2048; e += 256) {
    int row = e >> 8, u = e & 255;
    const float* cr = sr + row * FSTR;
    const float* ci = si + row * FSTR;
    q4[e] = make_float4(cr[2 * u], ci[2 * u], cr[2 * u + 1], ci[2 * u + 1]);
  }
}

// forward FFT over 8 adjacent columns per block (in-place on xf).
__global__ __launch_bounds__(256) void k_fft_cols(float2* __restrict__ xf) {
  __shared__ float sr[8 * FSTR], si[8 * FSTR], twr[256], twi[256];
  int t = threadIdx.x;
  int img = blockIdx.x >> 6;
  int c0 = (blockIdx.x & 63) << 3;
  init_tw(twr, twi, t);
  float2* base = xf + (size_t)img * NPIX + c0;
  for (int e = t; e < 2048; e += 256) {
    int a = e & 31, q = (e >> 5) & 3, b = e >> 7;
    int r = (a << 4) | b;
    float4 f = *(const float4*)(base + (size_t)r * 512 + 2 * q);
    int rr = brev9(r);
    sr[(2 * q) * FSTR + rr]     = f.x;  si[(2 * q) * FSTR + rr]     = f.y;
    sr[(2 * q + 1) * FSTR + rr] = f.z;  si[(2 * q + 1) * FSTR + rr] = f.w;
  }
  fft512x8<true>(sr, si, twr, twi, t);
  for (int e = t; e < 2048; e += 256) {
    int r = e & 511, q = e >> 9;
    float4 f = make_float4(sr[(2 * q) * FSTR + r], si[(2 * q) * FSTR + r],
                           sr[(2 * q + 1) * FSTR + r], si[(2 * q + 1) * FSTR + r]);
    *(float4*)(base + (size_t)r * 512 + 2 * q) = f;
  }
}

// xmag[b][c][h][w] = log10(|xf[(b+4)%8][(c+2)%3][(h+256)%512][(w+256)%512]| + 1)
__global__ __launch_bounds__(256) void k_xmag(const float2* __restrict__ xf,
                                              float* __restrict__ xmag) {
  int idx = blockIdx.x * 256 + threadIdx.x;
  int w = idx & 511;
  int h = (idx >> 9) & 511;
  int bc = idx >> 18;
  int b = bc / 3, c = bc - 3 * b;
  int simg = ((b + 4) & 7) * 3 + ((c + 2) % 3);
  float2 v = xf[(size_t)simg * NPIX + (size_t)((h + 256) & 511) * 512 + ((w + 256) & 511)];
  xmag[idx] = log10f(sqrtf(v.x * v.x + v.y * v.y) + 1.0f);
}

// conv1: 6->16, 512x512, pad1, relu, 2x2 avgpool -> [b][16][256][256]
// grid (4, 32, 16); 3 rounds x 2 staged ics per barrier.
__global__ __launch_bounds__(256) void k_conv1(const float* __restrict__ x,
                                               const float* __restrict__ xmag,
                                               const float* __restrict__ w1,
                                               const float* __restrict__ b1,
                                               float* __restrict__ out) {
  __shared__ float tile[2][18 * 132];
  const int t = threadIdx.x;
  const int tx = t & 31, ty = t >> 5;
  const int PC0 = blockIdx.x * 64;
  const int PR0 = blockIdx.y * 8;
  const int b  = blockIdx.z >> 1;
  const int og = (blockIdx.z & 1) * 8;
  const int R0 = PR0 * 2 - 1;
  const int C0 = PC0 * 2 - 1;

  float acc[8][8];
  #pragma unroll
  for (int o = 0; o < 8; o++)
    #pragma unroll
    for (int q = 0; q < 8; q++) acc[o][q] = 0.0f;

  for (int r = 0; r < 3; r++) {
    int ic0 = 2 * r;
    const float* src0 = (ic0 < 3)     ? (x + (size_t)(b * 3 + ic0) * NPIX)
                                      : (xmag + (size_t)(b * 3 + ic0 - 3) * NPIX);
    const float* src1 = (ic0 + 1 < 3) ? (x + (size_t)(b * 3 + ic0 + 1) * NPIX)
                                      : (xmag + (size_t)(b * 3 + ic0 - 2) * NPIX);
    __syncthreads();
    for (int e = t; e < 18 * 130; e += 256) {
      int i = e / 130, j = e - i * 130;
      int rr = R0 + i, cc = C0 + j;
      bool ok = ((unsigned)rr < 512u) & ((unsigned)cc < 512u);
      int go = rr * 512 + cc;
      int lo = i * 132 + j;
      tile[0][lo] = ok ? src0[go] : 0.0f;
      tile[1][lo] = ok ? src1[go] : 0.0f;
    }
    __syncthreads();
    #pragma unroll
    for (int c2 = 0; c2 < 2; c2++) {
      int ic = ic0 + c2;
      float patch[4][6];
      #pragma unroll
      for (int dy = 0; dy < 4; dy++) {
        const float* rp = tile[c2] + (2 * ty + dy) * 132 + 4 * tx;
        float4 f = *(const float4*)rp;
        float2 g = *(const float2*)(rp + 4);
        patch[dy][0] = f.x; patch[dy][1] = f.y; patch[dy][2] = f.z;
        patch[dy][3] = f.w; patch[dy][4] = g.x; patch[dy][5] = g.y;
      }
      #pragma unroll
      for (int o = 0; o < 8; o++) {
        const float* wk = w1 + (size_t)((og + o) * 6 + ic) * 9;
        float k0 = wk[0], k1 = wk[1], k2 = wk[2], k3 = wk[3], k4 = wk[4],
              k5 = wk[5], k6 = wk[6], k7 = wk[7], k8 = wk[8];
        #pragma unroll
        for (int py = 0; py < 2; py++)
          #pragma unroll
          for (int px = 0; px < 4; px++) {
            acc[o][py * 4 + px] +=
                k0 * patch[py][px]     + k1 * patch[py][px + 1]     + k2 * patch[py][px + 2]
              + k3 * patch[py + 1][px] + k4 * patch[py + 1][px + 1] + k5 * patch[py + 1][px + 2]
              + k6 * patch[py + 2][px] + k7 * patch[py + 2][px + 1] + k8 * patch[py + 2][px + 2];
          }
      }
    }
  }
  #pragma unroll
  for (int o = 0; o < 8; o++) {
    float bias = b1[og + o];
    float p0 = fmaxf(acc[o][0] + bias, 0.0f) + fmaxf(acc[o][1] + bias, 0.0f)
             + fmaxf(acc[o][4] + bias, 0.0f) + fmaxf(acc[o][5] + bias, 0.0f);
    float p1 = fmaxf(acc[o][2] + bias, 0.0f) + fmaxf(acc[o][3] + bias, 0.0f)
             + fmaxf(acc[o][6] + bias, 0.0f) + fmaxf(acc[o][7] + bias, 0.0f);
    float2* q = (float2*)(out + ((size_t)(b * 16 + og + o) * 256 + PR0 + ty) * 256 + PC0 + 2 * tx);
    *q = make_float2(p0 * 0.25f, p1 * 0.25f);
  }
}

// conv2: 16->32, 256x256, pad1, relu, pool. Output is NOT materialized:
// the pooled map is reduced to 9 stats per (b,oc): T, R0, R127, C0, C127,
// corners c00,c0e,ce0,cee -> S[b][32][9]. (conv3+mean is linear, so it
// collapses to a matvec over these stats in k_fc.)
// grid (2, 16, 32); 4 rounds x 4 staged ics.
__global__ __launch_bounds__(256) void k_conv2(const float* __restrict__ in,
                                               const float* __restrict__ w2,
                                               const float* __restrict__ b2,
                                               float* __restrict__ S) {
  __shared__ float tile[4][18 * 132];
  const int t = threadIdx.x;
  const int tx = t & 31, ty = t >> 5;
  const int bx = blockIdx.x, by = blockIdx.y;
  const int PC0 = bx * 64;
  const int PR0 = by * 8;
  const int b  = blockIdx.z >> 2;
  const int og = (blockIdx.z & 3) * 8;
  const int R0 = PR0 * 2 - 1;
  const int C0 = PC0 * 2 - 1;

  float acc[8][8];
  #pragma unroll
  for (int o = 0; o < 8; o++)
    #pragma unroll
    for (int q = 0; q < 8; q++) acc[o][q] = 0.0f;

  for (int r = 0; r < 4; r++) {
    const float* src = in + (size_t)(b * 16 + 4 * r) * 65536;
    __syncthreads();
    for (int e = t; e < 18 * 130; e += 256) {
      int i = e / 130, j = e - i * 130;
      int rr = R0 + i, cc = C0 + j;
      bool ok = ((unsigned)rr < 256u) & ((unsigned)cc < 256u);
      int go = rr * 256 + cc;
      int lo = i * 132 + j;
      tile[0][lo] = ok ? src[go] : 0.0f;
      tile[1][lo] = ok ? src[go + 65536] : 0.0f;
      tile[2][lo] = ok ? src[go + 131072] : 0.0f;
      tile[3][lo] = ok ? src[go + 196608] : 0.0f;
    }
    __syncthreads();
    #pragma unroll
    for (int c4 = 0; c4 < 4; c4++) {
      int ic = 4 * r + c4;
      float patch[4][6];
      #pragma unroll
      for (int dy = 0; dy < 4; dy++) {
        const float* rp = tile[c4] + (2 * ty + dy) * 132 + 4 * tx;
        float4 f = *(const float4*)rp;
        float2 g = *(const float2*)(rp + 4);
        patch[dy][0] = f.x; patch[dy][1] = f.y; patch[dy][2] = f.z;
        patch[dy][3] = f.w; patch[dy][4] = g.x; patch[dy][5] = g.y;
      }
      #pragma unroll
      for (int o = 0; o < 8; o++) {
        const float* wk = w2 + (size_t)((og + o) * 16 + ic) * 9;
        float k0 = wk[0], k1 = wk[1], k2 = wk[2], k3 = wk[3], k4 = wk[4],
              k5 = wk[5], k6 = wk[6], k7 = wk[7], k8 = wk[8];
        #pragma unroll
        for (int py = 0; py < 2; py++)
          #pragma unroll
          for (int px = 0; px < 4; px++) {
            acc[o][py * 4 + px] +=
                k0 * patch[py][px]     + k1 * patch[py][px + 1]     + k2 * patch[py][px + 2]
              + k3 * patch[py + 1][px] + k4 * patch[py + 1][px + 1] + k5 * patch[py + 1][px + 2]
              + k6 * patch[py + 2][px] + k7 * patch[py + 2][px + 1] + k8 * patch[py + 2][px + 2];
          }
      }
    }
  }

  const int lane = t & 63;
  #pragma unroll
  for (int o = 0; o < 8; o++) {
    float bias = b2[og + o];
    float p0 = (fmaxf(acc[o][0] + bias, 0.0f) + fmaxf(acc[o][1] + bias, 0.0f)
              + fmaxf(acc[o][4] + bias, 0.0f) + fmaxf(acc[o][5] + bias, 0.0f)) * 0.25f;
    float p1 = (fmaxf(acc[o][2] + bias, 0.0f) + fmaxf(acc[o][3] + bias, 0.0f)
              + fmaxf(acc[o][6] + bias, 0.0f) + fmaxf(acc[o][7] + bias, 0.0f)) * 0.25f;
    float* Sb = S + (size_t)(b * 32 + og + o) * 9;
    // total sum
    float ts = p0 + p1;
    #pragma unroll
    for (int off = 32; off > 0; off >>= 1) ts += __shfl_down(ts, off);
    if (lane == 0) atomicAdd(&Sb[0], ts);
    // row edges
    if (by == 0) {
      float v = (ty == 0) ? (p0 + p1) : 0.0f;
      #pragma unroll
      for (int off = 32; off > 0; off >>= 1) v += __shfl_down(v, off);
      if (lane == 0 && v != 0.0f) atomicAdd(&Sb[1], v);
      if (lane == 0 && ty <= 1 && v == 0.0f) atomicAdd(&Sb[1], v);  // keep atomic count uniform-ish (no-op)
    }
    if (by == 15) {
      float v = (ty == 7) ? (p0 + p1) : 0.0f;
      #pragma unroll
      for (int off = 32; off > 0; off >>= 1) v += __shfl_down(v, off);
      if (lane == 0) atomicAdd(&Sb[2], v);
    }
    // col edges
    if (bx == 0) {
      float v = (tx == 0) ? p0 : 0.0f;
      #pragma unroll
      for (int off = 32; off > 0; off >>= 1) v += __shfl_down(v, off);
      if (lane == 0) atomicAdd(&Sb[3], v);
    }
    if (bx == 1) {
      float v = (tx == 31) ? p1 : 0.0f;
      #pragma unroll
      for (int off = 32; off > 0; off >>= 1) v += __shfl_down(v, off);
      if (lane == 0) atomicAdd(&Sb[4], v);
    }
    // corners (each written by exactly one thread of one block)
    if (bx == 0 && by == 0  && t == 0)   Sb[5] = p0;   // [0][0]
    if (bx == 1 && by == 0  && t == 31)  Sb[6] = p1;   // [0][127]
    if (bx == 0 && by == 15 && t == 224) Sb[7] = p0;   // [127][0]
    if (bx == 1 && by == 15 && t == 255) Sb[8] = p1;   // [127][127]
  }
}

// k_fc: stats -> conv3-mean (matvec) -> FC1 -> FC2 -> leaky_relu. Single block.
__global__ __launch_bounds__(256) void k_fc(const float* __restrict__ S,
                                            const float* __restrict__ w3,
                                            const float* __restrict__ b3,
                                            const float* __restrict__ fw1,
                                            const float* __restrict__ fb1,
                                            const float* __restrict__ fw2,
                                            const float* __restrict__ fb2,
                                            float* __restrict__ vs_out) {
  __shared__ float Sp[2304];   // 8 x 32 x 9 window sums
  __shared__ float y[512];     // 8 x 64
  __shared__ float h1[2048];   // 8 x 256
  int t = threadIdx.x;
  // Sp[b][ic][dy*3+dx] = valid-window sum for that tap
  for (int e = t; e < 2304; e += 256) {
    int cell = e / 9, k = e - 9 * cell;
    int dy = k / 3, dx = k - 3 * dy;
    const float* s = S + cell * 9;
    float v = s[0];
    if (dy == 0) v -= s[2];          // exclude row127
    if (dy == 2) v -= s[1];          // exclude row0
    if (dx == 0) v -= s[4];          // exclude col127
    if (dx == 2) v -= s[3];          // exclude col0
    if (dy == 0 && dx == 0) v += s[8];
    if (dy == 0 && dx == 2) v += s[7];
    if (dy == 2 && dx == 0) v += s[6];
    if (dy == 2 && dx == 2) v += s[5];
    Sp[e] = v;
  }
  __syncthreads();
  // y[b][o] = b3[o] + (w3[o] . Sp[b]) / 16384
  for (int e = t; e < 512; e += 256) {
    int b = e >> 6, o = e & 63;
    const float* wrow = w3 + (size_t)o * 288;
    const float* sp = Sp + b * 288;
    float s = 0.0f;
    #pragma unroll 4
    for (int k = 0; k < 288; k++) s += wrow[k] * sp[k];
    y[e] = b3[o] + s * (1.0f / 16384.0f);
  }
  __syncthreads();
  for (int e = t; e < 2048; e += 256) {
    int b = e >> 8, j = e & 255;
    float s = fb1[j];
    for (int k = 0; k < 64; k++) s += y[b * 64 + k] * fw1[j * 64 + k];
    h1[e] = s;
  }
  __syncthreads();
  for (int e = t; e < 800; e += 256) {
    int b = e / 100, i = e - 100 * b;
    float s = fb2[i];
    for (int j = 0; j < 256; j++) s += h1[b * 256 + j] * fw2[i * 256 + j];
    vs_out[e] = (s >= 0.0f) ? s : 0.01f * s;
  }
}

// fq_mask[b][h][w] = value_set[b][searchsorted(radius_set, dist(h,w), 'left').clip(0,99)]
__global__ __launch_bounds__(256) void k_mask(const float* __restrict__ vs,
                                              float* __restrict__ fq_mask) {
  int idx = blockIdx.x * 256 + threadIdx.x;
  int h = idx >> 9, w = idx & 511;
  float da = (float)h - 256.0f, db = (float)w - 256.0f;
  float dist = sqrtf(da * da + db * db);
  int lo = 0, hi = 100;
  while (lo < hi) {
    int mid = (lo + hi) >> 1;
    float r = (362.03867196751236f * (float)(mid + 1)) * 0.01f;
    if (r < dist) lo = mid + 1; else hi = mid;
  }
  int bin = lo > 99 ? 99 : lo;
  #pragma unroll
  for (int b = 0; b < 8; b++)
    fq_mask[(size_t)b * NPIX + idx] = vs[b * 100 + bin];
}

// inverse FFT over 8 rows per block, spectrum modulation fused on load.
__global__ __launch_bounds__(256) void k_ifft_rows_mod(float2* __restrict__ xf,
                                                       const float* __restrict__ fq_mask) {
  __shared__ float sr[8 * FSTR], si[8 * FSTR], twr[256], twi[256];
  int t = threadIdx.x;
  int img = blockIdx.x >> 6;
  int r0 = (blockIdx.x & 63) << 3;
  int bm = ((img / 3) + 4) & 7;
  init_tw(twr, twi, t);
  const float* mbase = fq_mask + (size_t)bm * NPIX;
  float4* base4 = (float4*)(xf + (size_t)img * NPIX + (size_t)r0 * 512);
  for (int e = t; e < 2048; e += 256) {
    int u = (e & 3) | (((e >> 2) & 15) << 3) | (((e >> 6) & 1) << 2) | (((e >> 7) & 1) << 7);
    int row = e >> 8;
    float4 f = base4[row * 256 + u];
    int p0 = 2 * u;
    const float* mrow = mbase + (size_t)((r0 + row + 256) & 511) * 512;
    float2 m = *(const float2*)(mrow + ((p0 + 256) & 511));
    int rr0 = brev9(p0);
    float* cr = sr + row * FSTR;
    float* ci = si + row * FSTR;
    cr[rr0]       = f.x * m.x;  ci[rr0]       = f.y * m.x;
    cr[rr0 + 256] = f.z * m.y;  ci[rr0 + 256] = f.w * m.y;
  }
  fft512x8<false>(sr, si, twr, twi, t);
  for (int e = t; e < 2048; e += 256) {
    int row = e >> 8, u = e & 255;
    const float* cr = sr + row * FSTR;
    const float* ci = si + row * FSTR;
    base4[e] = make_float4(cr[2 * u], ci[2 * u], cr[2 * u + 1], ci[2 * u + 1]);
  }
}

// inverse FFT over 8 columns per block, scale 1/N, clip -> lowpass.
__global__ __launch_bounds__(256) void k_ifft_cols_out(const float2* __restrict__ xf,
                                                       float* __restrict__ lowpass) {
  __shared__ float sr[8 * FSTR], si[8 * FSTR], twr[256], twi[256];
  int t = threadIdx.x;
  int img = blockIdx.x >> 6;
  int c0 = (blockIdx.x & 63) << 3;
  init_tw(twr, twi, t);
  const float2* base = xf + (size_t)img * NPIX + c0;
  for (int e = t; e < 2048; e += 256) {
    int a = e & 31, q = (e >> 5) & 3, b = e >> 7;
    int r = (a << 4) | b;
    float4 f = *(const float4*)(base + (size_t)r * 512 + 2 * q);
    int rr = brev9(r);
    sr[(2 * q) * FSTR + rr]     = f.x;  si[(2 * q) * FSTR + rr]     = f.y;
    sr[(2 * q + 1) * FSTR + rr] = f.z;  si[(2 * q + 1) * FSTR + rr] = f.w;
  }
  fft512x8<false>(sr, si, twr, twi, t);
  const float sc = 1.0f / 262144.0f;
  float* obase = lowpass + (size_t)img * NPIX + c0;
  for (int e = t; e < 2048; e += 256) {
    int r = e & 511, q = e >> 9;
    float v0 = fminf(fmaxf(sr[(2 * q) * FSTR + r] * sc, 0.0f), 1.0f);
    float v1 = fminf(fmaxf(sr[(2 * q + 1) * FSTR + r] * sc, 0.0f), 1.0f);
    *(float2*)(obase + (size_t)r * 512 + 2 * q) = make_float2(v0, v1);
  }
}

extern "C" void kernel_launch(void* const* d_in, const int* in_sizes, int n_in,
                              void* d_out, int out_size, void* d_ws, size_t ws_size,
                              hipStream_t stream) {
  const float* x   = (const float*)d_in[0];
  const float* w1  = (const float*)d_in[1];
  const float* b1  = (const float*)d_in[2];
  const float* w2  = (const float*)d_in[3];
  const float* b2  = (const float*)d_in[4];
  const float* w3  = (const float*)d_in[5];
  const float* b3  = (const float*)d_in[6];
  const float* fw1 = (const float*)d_in[7];
  const float* fb1 = (const float*)d_in[8];
  const float* fw2 = (const float*)d_in[9];
  const float* fb2 = (const float*)d_in[10];

  float* lowpass = (float*)d_out;            // 8*3*512*512
  float* fq_mask = lowpass + 6291456;        // 8*512*512
  float* vs      = fq_mask + 2097152;        // 8*100

  float* base    = (float*)d_ws;
  float2* xf     = (float2*)base;            // 12582912 floats
  float* xmag    = base + 12582912;          // 6291456 floats
  float* pooled1 = xmag + 6291456;           // 8388608 floats
  float* S       = pooled1 + 8388608;        // 8*32*9 = 2304 floats

  k_fft_rows<<<dim3(24 * 64), 256, 0, stream>>>(x, xf);
  k_fft_cols<<<dim3(24 * 64), 256, 0, stream>>>(xf);

  k_xmag<<<6291456 / 256, 256, 0, stream>>>(xf, xmag);

  k_conv1<<<dim3(4, 32, 16), 256, 0, stream>>>(x, xmag, w1, b1, pooled1);
  hipMemsetAsync(S, 0, 2304 * sizeof(float), stream);
  k_conv2<<<dim3(2, 16, 32), 256, 0, stream>>>(pooled1, w2, b2, S);

  k_fc<<<1, 256, 0, stream>>>(S, w3, b3, fw1, fb1, fw2, fb2, vs);
  k_mask<<<1024, 256, 0, stream>>>(vs, fq_mask);

  k_ifft_rows_mod<<<dim3(24 * 64), 256, 0, stream>>>(xf, fq_mask);
  k_ifft_cols_out<<<dim3(24 * 64), 256, 0, stream>>>(xf, lowpass);
}

// Round 5
// 453.505 us; speedup vs baseline: 1.6092x; 1.6092x over previous
//
#include <hip/hip_runtime.h>
#include <math.h>

#define NPIX 262144   // 512*512
#define FSTR 513      // LDS column stride for batch-8 FFT (pad 512+1)

__device__ __forceinline__ int brev9(int i) { return (int)(__brev((unsigned)i) >> 23); }

__device__ __forceinline__ void init_tw(float* twr, float* twi, int t) {
  if (t < 256) {
    float ang = -3.14159265358979323846f * (float)t / 256.0f;
    float s, c;
    sincosf(ang, &s, &c);
    twr[t] = c; twi[t] = s;
  }
}

// 8 x 512-pt radix-2 DIT FFTs in LDS, column-major: element p of FFT c at
// [c*FSTR + p]. 256 threads: c = t>>5, 32 threads x 8 butterflies/stage/FFT.
template<bool FWD>
__device__ __forceinline__ void fft512x8(float* __restrict__ sr, float* __restrict__ si,
                                         const float* __restrict__ twr,
                                         const float* __restrict__ twi, int t) {
  const int c  = t >> 5;
  const int k0 = t & 31;
  float* cr = sr + c * FSTR;
  float* ci = si + c * FSTR;
  #pragma unroll
  for (int s = 0; s < 9; s++) {
    const int half = 1 << s;
    __syncthreads();
    #pragma unroll
    for (int m = 0; m < 8; m++) {
      int k  = k0 + 32 * m;
      int j  = k & (half - 1);
      int k2 = ((k >> s) << (s + 1)) | j;
      int tk = j << (8 - s);
      float wr = twr[tk];
      float wi = FWD ? twi[tk] : -twi[tk];
      float vr = cr[k2 + half], vi = ci[k2 + half];
      float tr = vr * wr - vi * wi;
      float ti = vr * wi + vi * wr;
      float ur = cr[k2], ui = ci[k2];
      cr[k2] = ur + tr;        ci[k2] = ui + ti;
      cr[k2 + half] = ur - tr; ci[k2 + half] = ui - ti;
    }
  }
  __syncthreads();
}

// forward FFT over 8 contiguous rows per block (real input).
__global__ __launch_bounds__(256) void k_fft_rows(const float* __restrict__ x,
                                                  float2* __restrict__ xf) {
  __shared__ float sr[8 * FSTR], si[8 * FSTR], twr[256], twi[256];
  int t = threadIdx.x;
  int img = blockIdx.x >> 6;
  int r0 = (blockIdx.x & 63) << 3;
  init_tw(twr, twi, t);
  const float4* p4 = (const float4*)(x + (size_t)img * NPIX + (size_t)r0 * 512);
  for (int e = t; e < 1024; e += 256) {
    int row = e >> 7, w = e & 127;
    float4 f = p4[e];
    float* cr = sr + row * FSTR;
    float* ci = si + row * FSTR;
    int p = 4 * w;
    cr[brev9(p)]     = f.x;  ci[brev9(p)]     = 0.0f;
    cr[brev9(p + 1)] = f.y;  ci[brev9(p + 1)] = 0.0f;
    cr[brev9(p + 2)] = f.z;  ci[brev9(p + 2)] = 0.0f;
    cr[brev9(p + 3)] = f.w;  ci[brev9(p + 3)] = 0.0f;
  }
  fft512x8<true>(sr, si, twr, twi, t);
  float4* q4 = (float4*)(xf + (size_t)img * NPIX + (size_t)r0 * 512);
  for (int e = t; e < 2048; e += 256) {
    int row = e >> 8, u = e & 255;
    const float* cr = sr + row * FSTR;
    const float* ci = si + row * FSTR;
    q4[e] = make_float4(cr[2 * u], ci[2 * u], cr[2 * u + 1], ci[2 * u + 1]);
  }
}

// forward FFT over 8 adjacent columns per block (in-place on xf).
__global__ __launch_bounds__(256) void k_fft_cols(float2* __restrict__ xf) {
  __shared__ float sr[8 * FSTR], si[8 * FSTR], twr[256], twi[256];
  int t = threadIdx.x;
  int img = blockIdx.x >> 6;
  int c0 = (blockIdx.x & 63) << 3;
  init_tw(twr, twi, t);
  float2* base = xf + (size_t)img * NPIX + c0;
  for (int e = t; e < 2048; e += 256) {
    int a = e & 31, q = (e >> 5) & 3, b = e >> 7;
    int r = (a << 4) | b;
    float4 f = *(const float4*)(base + (size_t)r * 512 + 2 * q);
    int rr = brev9(r);
    sr[(2 * q) * FSTR + rr]     = f.x;  si[(2 * q) * FSTR + rr]     = f.y;
    sr[(2 * q + 1) * FSTR + rr] = f.z;  si[(2 * q + 1) * FSTR + rr] = f.w;
  }
  fft512x8<true>(sr, si, twr, twi, t);
  for (int e = t; e < 2048; e += 256) {
    int r = e & 511, q = e >> 9;
    float4 f = make_float4(sr[(2 * q) * FSTR + r], si[(2 * q) * FSTR + r],
                           sr[(2 * q + 1) * FSTR + r], si[(2 * q + 1) * FSTR + r]);
    *(float4*)(base + (size_t)r * 512 + 2 * q) = f;
  }
}

// xmag[b][c][h][w] = log10(|xf[(b+4)%8][(c+2)%3][(h+256)%512][(w+256)%512]| + 1)
__global__ __launch_bounds__(256) void k_xmag(const float2* __restrict__ xf,
                                              float* __restrict__ xmag) {
  int idx = blockIdx.x * 256 + threadIdx.x;
  int w = idx & 511;
  int h = (idx >> 9) & 511;
  int bc = idx >> 18;
  int b = bc / 3, c = bc - 3 * b;
  int simg = ((b + 4) & 7) * 3 + ((c + 2) % 3);
  float2 v = xf[(size_t)simg * NPIX + (size_t)((h + 256) & 511) * 512 + ((w + 256) & 511)];
  xmag[idx] = log10f(sqrtf(v.x * v.x + v.y * v.y) + 1.0f);
}

// conv1: 6->16, 512x512, pad1, relu, 2x2 avgpool -> [b][16][256][256]
// grid (4, 32, 16). Double-buffered LDS staging, 1 ic per round.
__global__ __launch_bounds__(256) void k_conv1(const float* __restrict__ x,
                                               const float* __restrict__ xmag,
                                               const float* __restrict__ w1,
                                               const float* __restrict__ b1,
                                               float* __restrict__ out) {
  __shared__ float tile[2][18 * 132 + 8];
  const int t = threadIdx.x;
  const int tx = t & 31, ty = t >> 5;
  const int PC0 = blockIdx.x * 64;
  const int PR0 = blockIdx.y * 8;
  const int b  = blockIdx.z >> 1;
  const int og = (blockIdx.z & 1) * 8;
  const int R0 = PR0 * 2 - 1;
  const int C0 = PC0 * 2 - 1;

  // precompute staging slots (10 per thread, 2340 total)
  int li[10], gi[10];
  bool okf[10];
  #pragma unroll
  for (int k = 0; k < 10; k++) {
    int e = t + 256 * k;
    bool valid = e < 2340;
    int i = e / 130, j = e - i * 130;
    int rr = R0 + i, cc = C0 + j;
    bool ok = valid && ((unsigned)rr < 512u) && ((unsigned)cc < 512u);
    li[k] = valid ? (i * 132 + j) : (18 * 132);   // dummy slot
    gi[k] = ok ? (rr * 512 + cc) : 0;
    okf[k] = ok;
  }

  float acc[8][8];
  #pragma unroll
  for (int o = 0; o < 8; o++)
    #pragma unroll
    for (int q = 0; q < 8; q++) acc[o][q] = 0.0f;

  const float* xb = x + (size_t)(b * 3) * NPIX;
  const float* mb = xmag + (size_t)(b * 3) * NPIX;

  float ld[10];
  #pragma unroll
  for (int k = 0; k < 10; k++) ld[k] = okf[k] ? xb[gi[k]] : 0.0f;
  #pragma unroll
  for (int k = 0; k < 10; k++) tile[0][li[k]] = ld[k];
  __syncthreads();

  for (int ic = 0; ic < 6; ic++) {
    if (ic < 5) {
      const float* sn = (ic + 1 < 3) ? (xb + (size_t)(ic + 1) * NPIX)
                                     : (mb + (size_t)(ic - 2) * NPIX);
      #pragma unroll
      for (int k = 0; k < 10; k++) ld[k] = okf[k] ? sn[gi[k]] : 0.0f;
    }
    const float* cur = tile[ic & 1];
    float patch[4][6];
    #pragma unroll
    for (int dy = 0; dy < 4; dy++) {
      const float* rp = cur + (2 * ty + dy) * 132 + 4 * tx;
      float4 f = *(const float4*)rp;
      float2 g = *(const float2*)(rp + 4);
      patch[dy][0] = f.x; patch[dy][1] = f.y; patch[dy][2] = f.z;
      patch[dy][3] = f.w; patch[dy][4] = g.x; patch[dy][5] = g.y;
    }
    #pragma unroll
    for (int o = 0; o < 8; o++) {
      const float* wk = w1 + (size_t)((og + o) * 6 + ic) * 9;
      float k0 = wk[0], k1 = wk[1], k2 = wk[2], k3 = wk[3], k4 = wk[4],
            k5 = wk[5], k6 = wk[6], k7 = wk[7], k8 = wk[8];
      #pragma unroll
      for (int py = 0; py < 2; py++)
        #pragma unroll
        for (int px = 0; px < 4; px++) {
          acc[o][py * 4 + px] +=
              k0 * patch[py][px]     + k1 * patch[py][px + 1]     + k2 * patch[py][px + 2]
            + k3 * patch[py + 1][px] + k4 * patch[py + 1][px + 1] + k5 * patch[py + 1][px + 2]
            + k6 * patch[py + 2][px] + k7 * patch[py + 2][px + 1] + k8 * patch[py + 2][px + 2];
        }
    }
    if (ic < 5) {
      __syncthreads();
      float* nxt = tile[(ic + 1) & 1];
      #pragma unroll
      for (int k = 0; k < 10; k++) nxt[li[k]] = ld[k];
      __syncthreads();
    }
  }
  #pragma unroll
  for (int o = 0; o < 8; o++) {
    float bias = b1[og + o];
    float p0 = fmaxf(acc[o][0] + bias, 0.0f) + fmaxf(acc[o][1] + bias, 0.0f)
             + fmaxf(acc[o][4] + bias, 0.0f) + fmaxf(acc[o][5] + bias, 0.0f);
    float p1 = fmaxf(acc[o][2] + bias, 0.0f) + fmaxf(acc[o][3] + bias, 0.0f)
             + fmaxf(acc[o][6] + bias, 0.0f) + fmaxf(acc[o][7] + bias, 0.0f);
    float2* q = (float2*)(out + ((size_t)(b * 16 + og + o) * 256 + PR0 + ty) * 256 + PC0 + 2 * tx);
    *q = make_float2(p0 * 0.25f, p1 * 0.25f);
  }
}

// conv2: 16->32, 256x256, pad1, relu, pool. Output NOT materialized; reduced
// to 9 stats per (b,oc): T, R0, R127, C0, C127, 4 corners -> S[b][32][9].
// grid (2, 16, 32). Double-buffered LDS staging, 1 ic per round.
__global__ __launch_bounds__(256) void k_conv2(const float* __restrict__ in,
                                               const float* __restrict__ w2,
                                               const float* __restrict__ b2,
                                               float* __restrict__ S) {
  __shared__ float tile[2][18 * 132 + 8];
  const int t = threadIdx.x;
  const int tx = t & 31, ty = t >> 5;
  const int bx = blockIdx.x, by = blockIdx.y;
  const int PC0 = bx * 64;
  const int PR0 = by * 8;
  const int b  = blockIdx.z >> 2;
  const int og = (blockIdx.z & 3) * 8;
  const int R0 = PR0 * 2 - 1;
  const int C0 = PC0 * 2 - 1;

  int li[10], gi[10];
  bool okf[10];
  #pragma unroll
  for (int k = 0; k < 10; k++) {
    int e = t + 256 * k;
    bool valid = e < 2340;
    int i = e / 130, j = e - i * 130;
    int rr = R0 + i, cc = C0 + j;
    bool ok = valid && ((unsigned)rr < 256u) && ((unsigned)cc < 256u);
    li[k] = valid ? (i * 132 + j) : (18 * 132);
    gi[k] = ok ? (rr * 256 + cc) : 0;
    okf[k] = ok;
  }

  float acc[8][8];
  #pragma unroll
  for (int o = 0; o < 8; o++)
    #pragma unroll
    for (int q = 0; q < 8; q++) acc[o][q] = 0.0f;

  const float* inb = in + (size_t)(b * 16) * 65536;

  float ld[10];
  #pragma unroll
  for (int k = 0; k < 10; k++) ld[k] = okf[k] ? inb[gi[k]] : 0.0f;
  #pragma unroll
  for (int k = 0; k < 10; k++) tile[0][li[k]] = ld[k];
  __syncthreads();

  for (int ic = 0; ic < 16; ic++) {
    if (ic < 15) {
      const float* sn = inb + (size_t)(ic + 1) * 65536;
      #pragma unroll
      for (int k = 0; k < 10; k++) ld[k] = okf[k] ? sn[gi[k]] : 0.0f;
    }
    const float* cur = tile[ic & 1];
    float patch[4][6];
    #pragma unroll
    for (int dy = 0; dy < 4; dy++) {
      const float* rp = cur + (2 * ty + dy) * 132 + 4 * tx;
      float4 f = *(const float4*)rp;
      float2 g = *(const float2*)(rp + 4);
      patch[dy][0] = f.x; patch[dy][1] = f.y; patch[dy][2] = f.z;
      patch[dy][3] = f.w; patch[dy][4] = g.x; patch[dy][5] = g.y;
    }
    #pragma unroll
    for (int o = 0; o < 8; o++) {
      const float* wk = w2 + (size_t)((og + o) * 16 + ic) * 9;
      float k0 = wk[0], k1 = wk[1], k2 = wk[2], k3 = wk[3], k4 = wk[4],
            k5 = wk[5], k6 = wk[6], k7 = wk[7], k8 = wk[8];
      #pragma unroll
      for (int py = 0; py < 2; py++)
        #pragma unroll
        for (int px = 0; px < 4; px++) {
          acc[o][py * 4 + px] +=
              k0 * patch[py][px]     + k1 * patch[py][px + 1]     + k2 * patch[py][px + 2]
            + k3 * patch[py + 1][px] + k4 * patch[py + 1][px + 1] + k5 * patch[py + 1][px + 2]
            + k6 * patch[py + 2][px] + k7 * patch[py + 2][px + 1] + k8 * patch[py + 2][px + 2];
        }
    }
    if (ic < 15) {
      __syncthreads();
      float* nxt = tile[(ic + 1) & 1];
      #pragma unroll
      for (int k = 0; k < 10; k++) nxt[li[k]] = ld[k];
      __syncthreads();
    }
  }

  const int lane = t & 63;
  #pragma unroll
  for (int o = 0; o < 8; o++) {
    float bias = b2[og + o];
    float p0 = (fmaxf(acc[o][0] + bias, 0.0f) + fmaxf(acc[o][1] + bias, 0.0f)
              + fmaxf(acc[o][4] + bias, 0.0f) + fmaxf(acc[o][5] + bias, 0.0f)) * 0.25f;
    float p1 = (fmaxf(acc[o][2] + bias, 0.0f) + fmaxf(acc[o][3] + bias, 0.0f)
              + fmaxf(acc[o][6] + bias, 0.0f) + fmaxf(acc[o][7] + bias, 0.0f)) * 0.25f;
    float* Sb = S + (size_t)(b * 32 + og + o) * 9;
    // total sum: wave reduce, 4 atomics per block
    float ts = p0 + p1;
    #pragma unroll
    for (int off = 32; off > 0; off >>= 1) ts += __shfl_down(ts, off);
    if (lane == 0) atomicAdd(&Sb[0], ts);
    // edges: direct atomics from edge threads only
    if (by == 0  && ty == 0) atomicAdd(&Sb[1], p0 + p1);
    if (by == 15 && ty == 7) atomicAdd(&Sb[2], p0 + p1);
    if (bx == 0  && tx == 0) atomicAdd(&Sb[3], p0);
    if (bx == 1  && tx == 31) atomicAdd(&Sb[4], p1);
    // corners
    if (bx == 0 && by == 0  && t == 0)   Sb[5] = p0;
    if (bx == 1 && by == 0  && t == 31)  Sb[6] = p1;
    if (bx == 0 && by == 15 && t == 224) Sb[7] = p0;
    if (bx == 1 && by == 15 && t == 255) Sb[8] = p1;
  }
}

// k_fc: stats -> conv3-mean (matvec over 288 window sums) -> FC1 -> FC2 -> leaky.
__global__ __launch_bounds__(256) void k_fc(const float* __restrict__ S,
                                            const float* __restrict__ w3,
                                            const float* __restrict__ b3,
                                            const float* __restrict__ fw1,
                                            const float* __restrict__ fb1,
                                            const float* __restrict__ fw2,
                                            const float* __restrict__ fb2,
                                            float* __restrict__ vs_out) {
  __shared__ float Sp[2304];   // 8 x 32 x 9 window sums
  __shared__ float y[512];     // 8 x 64
  __shared__ float h1[2048];   // 8 x 256
  int t = threadIdx.x;
  for (int e = t; e < 2304; e += 256) {
    int cell = e / 9, k = e - 9 * cell;
    int dy = k / 3, dx = k - 3 * dy;
    const float* s = S + cell * 9;
    float v = s[0];
    if (dy == 0) v -= s[2];
    if (dy == 2) v -= s[1];
    if (dx == 0) v -= s[4];
    if (dx == 2) v -= s[3];
    if (dy == 0 && dx == 0) v += s[8];
    if (dy == 0 && dx == 2) v += s[7];
    if (dy == 2 && dx == 0) v += s[6];
    if (dy == 2 && dx == 2) v += s[5];
    Sp[e] = v;
  }
  __syncthreads();
  for (int e = t; e < 512; e += 256) {
    int b = e >> 6, o = e & 63;
    const float* wrow = w3 + (size_t)o * 288;
    const float* sp = Sp + b * 288;
    float s = 0.0f;
    #pragma unroll 4
    for (int k = 0; k < 288; k++) s += wrow[k] * sp[k];
    y[e] = b3[o] + s * (1.0f / 16384.0f);
  }
  __syncthreads();
  for (int e = t; e < 2048; e += 256) {
    int b = e >> 8, j = e & 255;
    float s = fb1[j];
    for (int k = 0; k < 64; k++) s += y[b * 64 + k] * fw1[j * 64 + k];
    h1[e] = s;
  }
  __syncthreads();
  for (int e = t; e < 800; e += 256) {
    int b = e / 100, i = e - 100 * b;
    float s = fb2[i];
    for (int j = 0; j < 256; j++) s += h1[b * 256 + j] * fw2[i * 256 + j];
    vs_out[e] = (s >= 0.0f) ? s : 0.01f * s;
  }
}

// fq_mask[b][h][w] = value_set[b][searchsorted(radius_set, dist(h,w), 'left').clip(0,99)]
__global__ __launch_bounds__(256) void k_mask(const float* __restrict__ vs,
                                              float* __restrict__ fq_mask) {
  int idx = blockIdx.x * 256 + threadIdx.x;
  int h = idx >> 9, w = idx & 511;
  float da = (float)h - 256.0f, db = (float)w - 256.0f;
  float dist = sqrtf(da * da + db * db);
  int lo = 0, hi = 100;
  while (lo < hi) {
    int mid = (lo + hi) >> 1;
    float r = (362.03867196751236f * (float)(mid + 1)) * 0.01f;
    if (r < dist) lo = mid + 1; else hi = mid;
  }
  int bin = lo > 99 ? 99 : lo;
  #pragma unroll
  for (int b = 0; b < 8; b++)
    fq_mask[(size_t)b * NPIX + idx] = vs[b * 100 + bin];
}

// inverse FFT over 8 rows per block, spectrum modulation fused on load.
__global__ __launch_bounds__(256) void k_ifft_rows_mod(float2* __restrict__ xf,
                                                       const float* __restrict__ fq_mask) {
  __shared__ float sr[8 * FSTR], si[8 * FSTR], twr[256], twi[256];
  int t = threadIdx.x;
  int img = blockIdx.x >> 6;
  int r0 = (blockIdx.x & 63) << 3;
  int bm = ((img / 3) + 4) & 7;
  init_tw(twr, twi, t);
  const float* mbase = fq_mask + (size_t)bm * NPIX;
  float4* base4 = (float4*)(xf + (size_t)img * NPIX + (size_t)r0 * 512);
  for (int e = t; e < 2048; e += 256) {
    int u = (e & 3) | (((e >> 2) & 15) << 3) | (((e >> 6) & 1) << 2) | (((e >> 7) & 1) << 7);
    int row = e >> 8;
    float4 f = base4[row * 256 + u];
    int p0 = 2 * u;
    const float* mrow = mbase + (size_t)((r0 + row + 256) & 511) * 512;
    float2 m = *(const float2*)(mrow + ((p0 + 256) & 511));
    int rr0 = brev9(p0);
    float* cr = sr + row * FSTR;
    float* ci = si + row * FSTR;
    cr[rr0]       = f.x * m.x;  ci[rr0]       = f.y * m.x;
    cr[rr0 + 256] = f.z * m.y;  ci[rr0 + 256] = f.w * m.y;
  }
  fft512x8<false>(sr, si, twr, twi, t);
  for (int e = t; e < 2048; e += 256) {
    int row = e >> 8, u = e & 255;
    const float* cr = sr + row * FSTR;
    const float* ci = si + row * FSTR;
    base4[e] = make_float4(cr[2 * u], ci[2 * u], cr[2 * u + 1], ci[2 * u + 1]);
  }
}

// inverse FFT over 8 columns per block, scale 1/N, clip -> lowpass.
__global__ __launch_bounds__(256) void k_ifft_cols_out(const float2* __restrict__ xf,
                                                       float* __restrict__ lowpass) {
  __shared__ float sr[8 * FSTR], si[8 * FSTR], twr[256], twi[256];
  int t = threadIdx.x;
  int img = blockIdx.x >> 6;
  int c0 = (blockIdx.x & 63) << 3;
  init_tw(twr, twi, t);
  const float2* base = xf + (size_t)img * NPIX + c0;
  for (int e = t; e < 2048; e += 256) {
    int a = e & 31, q = (e >> 5) & 3, b = e >> 7;
    int r = (a << 4) | b;
    float4 f = *(const float4*)(base + (size_t)r * 512 + 2 * q);
    int rr = brev9(r);
    sr[(2 * q) * FSTR + rr]     = f.x;  si[(2 * q) * FSTR + rr]     = f.y;
    sr[(2 * q + 1) * FSTR + rr] = f.z;  si[(2 * q + 1) * FSTR + rr] = f.w;
  }
  fft512x8<false>(sr, si, twr, twi, t);
  const float sc = 1.0f / 262144.0f;
  float* obase = lowpass + (size_t)img * NPIX + c0;
  for (int e = t; e < 2048; e += 256) {
    int r = e & 511, q = e >> 9;
    float v0 = fminf(fmaxf(sr[(2 * q) * FSTR + r] * sc, 0.0f), 1.0f);
    float v1 = fminf(fmaxf(sr[(2 * q + 1) * FSTR + r] * sc, 0.0f), 1.0f);
    *(float2*)(obase + (size_t)r * 512 + 2 * q) = make_float2(v0, v1);
  }
}

extern "C" void kernel_launch(void* const* d_in, const int* in_sizes, int n_in,
                              void* d_out, int out_size, void* d_ws, size_t ws_size,
                              hipStream_t stream) {
  const float* x   = (const float*)d_in[0];
  const float* w1  = (const float*)d_in[1];
  const float* b1  = (const float*)d_in[2];
  const float* w2  = (const float*)d_in[3];
  const float* b2  = (const float*)d_in[4];
  const float* w3  = (const float*)d_in[5];
  const float* b3  = (const float*)d_in[6];
  const float* fw1 = (const float*)d_in[7];
  const float* fb1 = (const float*)d_in[8];
  const float* fw2 = (const float*)d_in[9];
  const float* fb2 = (const float*)d_in[10];

  float* lowpass = (float*)d_out;            // 8*3*512*512
  float* fq_mask = lowpass + 6291456;        // 8*512*512
  float* vs      = fq_mask + 2097152;        // 8*100

  float* base    = (float*)d_ws;
  float2* xf     = (float2*)base;            // 12582912 floats
  float* xmag    = base + 12582912;          // 6291456 floats
  float* pooled1 = xmag + 6291456;           // 8388608 floats
  float* S       = pooled1 + 8388608;        // 8*32*9 = 2304 floats

  k_fft_rows<<<dim3(24 * 64), 256, 0, stream>>>(x, xf);
  k_fft_cols<<<dim3(24 * 64), 256, 0, stream>>>(xf);

  k_xmag<<<6291456 / 256, 256, 0, stream>>>(xf, xmag);

  k_conv1<<<dim3(4, 32, 16), 256, 0, stream>>>(x, xmag, w1, b1, pooled1);
  hipMemsetAsync(S, 0, 2304 * sizeof(float), stream);
  k_conv2<<<dim3(2, 16, 32), 256, 0, stream>>>(pooled1, w2, b2, S);

  k_fc<<<1, 256, 0, stream>>>(S, w3, b3, fw1, fb1, fw2, fb2, vs);
  k_mask<<<1024, 256, 0, stream>>>(vs, fq_mask);

  k_ifft_rows_mod<<<dim3(24 * 64), 256, 0, stream>>>(xf, fq_mask);
  k_ifft_cols_out<<<dim3(24 * 64), 256, 0, stream>>>(xf, lowpass);
}